// Round 13
// baseline (471.974 us; speedup 1.0000x reference)
//
#include <hip/hip_runtime.h>
#include <stdint.h>

// ---------------------------------------------------------------------------
// LinearAttention (B=4, S=4096, HID=1024, H=16, D=64), chunked formulation.
// Round 13: R12 config (best measured, 256.4 us) + occupancy-3 Wo GEMM:
// OUTF32 instance gets a 48 KB variant (2-buf loop, 4x32-row f32 epilogue)
// -> 3 blocks/CU.  QKV GEMM instance byte-identical to R12.
// ---------------------------------------------------------------------------

#define DEVI __device__ __forceinline__

typedef __attribute__((ext_vector_type(8))) short bf16x8;
typedef __attribute__((ext_vector_type(4))) float f32x4;
typedef unsigned short u16;

DEVI u16 f2bf(float f) {
  union { float f; uint32_t u; } x; x.f = f;
  return (u16)((x.u + 0x7FFFu + ((x.u >> 16) & 1u)) >> 16);  // RNE
}
DEVI float bf2f(u16 u) {
  union { uint32_t u; float f; } x; x.u = ((uint32_t)u) << 16;
  return x.f;
}
DEVI f32x4 mfma16(bf16x8 a, bf16x8 b, f32x4 c) {
  return __builtin_amdgcn_mfma_f32_16x16x32_bf16(a, b, c, 0, 0, 0);
}

typedef __attribute__((address_space(3))) void* lds_vp;
typedef const __attribute__((address_space(1))) void* glb_vp;
DEVI void gload_lds16(const void* g, void* l) {
  __builtin_amdgcn_global_load_lds((glb_vp)g, (lds_vp)l, 16, 0, 0);
}

static constexpr int Ss  = 4096;
static constexpr int Hh  = 16;
static constexpr int CC  = 64;          // chunk length
static constexpr int NCC = Ss / CC;     // 64 chunks

// ---------------------------------------------------------------------------
// prep: x (fp32)->bf16 (blocks 0..8191) and 4 weight transposes+cvt
// ---------------------------------------------------------------------------
__global__ __launch_bounds__(256) void prep_k(const float* __restrict__ x,
                                              const float* __restrict__ w0,
                                              const float* __restrict__ w1,
                                              const float* __restrict__ w2,
                                              const float* __restrict__ w3,
                                              u16* __restrict__ xbf,
                                              u16* __restrict__ dqkv,
                                              u16* __restrict__ dwo) {
  __shared__ float tl[32][33];
  const int bid = blockIdx.x;
  if (bid < 8192) {
    const int i = bid * 256 + threadIdx.x;
    const float4* p = (const float4*)(x + (size_t)i * 8);
    const float4 a = p[0], b = p[1];
    union { uint4 v; u16 s[8]; } u;
    u.s[0] = f2bf(a.x); u.s[1] = f2bf(a.y); u.s[2] = f2bf(a.z); u.s[3] = f2bf(a.w);
    u.s[4] = f2bf(b.x); u.s[5] = f2bf(b.y); u.s[6] = f2bf(b.z); u.s[7] = f2bf(b.w);
    ((uint4*)xbf)[i] = u.v;
    return;
  }
  const int wz = bid - 8192;
  const int z = wz >> 10, wl = wz & 1023;
  const int bx = wl & 31, by = wl >> 5;
  const float* in = (z == 0) ? w0 : (z == 1) ? w1 : (z == 2) ? w2 : w3;
  u16* out = (z < 3) ? (dqkv + (size_t)z * 1024 * 1024) : dwo;
  const int tx = threadIdx.x & 31, ty = threadIdx.x >> 5;
#pragma unroll
  for (int j = 0; j < 4; ++j)
    tl[ty + j * 8][tx] = in[(size_t)(by * 32 + ty + j * 8) * 1024 + bx * 32 + tx];
  __syncthreads();
#pragma unroll
  for (int j = 0; j < 4; ++j)
    out[(size_t)(bx * 32 + ty + j * 8) * 1024 + by * 32 + tx] = f2bf(tl[tx][ty + j * 8]);
}

// ---------------------------------------------------------------------------
// 128x256 GEMM, BK=32, 512 threads = 8 waves (2M x 4N), per-wave 64x64,
// acc[4][4], T2 swizzle, T5 setprio, XCD swizzle.
// OCC3=false (QKV): triple-buffered staging (72 KB), 2-tile lookahead, one
//   barrier/tile, vmcnt(3) gate.  2 blocks/CU.   [R12 path, byte-identical]
// OCC3=true (Wo): double-buffered staging (48 KB), stage(t+1)->vmcnt(3),
//   2 barriers/tile, f32 epilogue in 4x32-row passes (32 KB).  3 blocks/CU.
// ---------------------------------------------------------------------------
template <bool FUSED, bool OUTF32, bool OCC3>
__global__ __launch_bounds__(512, OCC3 ? 6 : 4)
void gemm128_k(const u16* __restrict__ A,
               const u16* __restrict__ BT,
               const float* __restrict__ b0,
               const float* __restrict__ b1,
               const float* __restrict__ b2,
               void* __restrict__ out,
               int M, int K) {
  constexpr int LDSN = OCC3 ? 24576 : 36864;   // u16: 48 KB / 72 KB
  constexpr int BOFF = OCC3 ? 8192 : 12288;    // B staging base (u16)
  __shared__ __attribute__((aligned(16))) u16 lds[LDSN];
  const int t = threadIdx.x, lane = t & 63, w = t >> 6;
  const int wm = w >> 2, wn = w & 3;   // 2M x 4N over 128x256

  // XCD-aware bijective swizzle (nwg % 8 == 0 for our grids)
  const int nx = gridDim.x;
  const int nwg = nx * gridDim.y;
  const int bid = blockIdx.y * nx + blockIdx.x;
  const int swz = (bid & 7) * (nwg >> 3) + (bid >> 3);
  const int bx = swz % nx, by = swz / nx;
  const int m0 = by * 128, n0 = bx * 256;

  const u16* gA = A + (size_t)m0 * K;
  const u16* gB = BT + (size_t)n0 * K;

  // staging: A slot [128][32] (8 KB); B slot [256][32] (16 KB).
  // Global k-chunk pre-XOR-swizzled (both-sides-or-neither, rule #21).
  const int sr = t >> 2;
  const int sc = (t & 3) ^ ((sr >> 1) & 3);
  auto stage = [&](int kt2, int buf) {
    const int kof = kt2 << 5;
    gload_lds16(gA + (size_t)sr * K + kof + sc * 8, lds + buf * 4096 + t * 8);
    gload_lds16(gB + (size_t)sr * K + kof + sc * 8, lds + BOFF + buf * 8192 + t * 8);
    gload_lds16(gB + (size_t)(sr + 128) * K + kof + sc * 8,
                lds + BOFF + buf * 8192 + 4096 + t * 8);
  };

  f32x4 acc[4][4];
#pragma unroll
  for (int i = 0; i < 4; ++i)
#pragma unroll
    for (int j = 0; j < 4; ++j) acc[i][j] = f32x4{0.f, 0.f, 0.f, 0.f};

  const int fr = lane & 15, kq = lane >> 4;
  const int arow0 = wm * 64 + fr;
  const int brow0 = wn * 64 + fr;
  const int nk = K >> 5;

  if constexpr (!OCC3) {
    // -------- R12 loop: 3 bufs, 2-tile lookahead, 1 barrier/tile --------
    stage(0, 0);
    stage(1, 1);
    int cb = 0, nb = 2;
    for (int kt = 0; kt < nk; ++kt) {
      if (kt + 1 < nk) asm volatile("s_waitcnt vmcnt(3)" ::: "memory");
      else             asm volatile("s_waitcnt vmcnt(0)" ::: "memory");
      __builtin_amdgcn_s_barrier();
      if (kt + 2 < nk) stage(kt + 2, nb);

      const u16* Ab = lds + cb * 4096;
      const u16* Bb = lds + BOFF + cb * 8192;
      bf16x8 af[4], bg[4];
#pragma unroll
      for (int fi = 0; fi < 4; ++fi) {
        const int row = arow0 + fi * 16;
        af[fi] = *(const bf16x8*)(Ab + row * 32 + ((kq ^ ((row >> 1) & 3)) << 3));
      }
#pragma unroll
      for (int fj = 0; fj < 4; ++fj) {
        const int row = brow0 + fj * 16;
        bg[fj] = *(const bf16x8*)(Bb + row * 32 + ((kq ^ ((row >> 1) & 3)) << 3));
      }
      asm volatile("s_waitcnt lgkmcnt(0)" ::: "memory");
      __builtin_amdgcn_sched_barrier(0);
      __builtin_amdgcn_s_setprio(1);
#pragma unroll
      for (int fi = 0; fi < 4; ++fi)
#pragma unroll
        for (int fj = 0; fj < 4; ++fj)
          acc[fi][fj] = mfma16(af[fi], bg[fj], acc[fi][fj]);
      __builtin_amdgcn_s_setprio(0);
      __builtin_amdgcn_sched_barrier(0);
      cb = (cb + 1 == 3) ? 0 : cb + 1;
      nb = (nb + 1 == 3) ? 0 : nb + 1;
    }
    __syncthreads();
  } else {
    // -------- R9 loop: 2 bufs, stage(t+1)->vmcnt(3), 2 barriers/tile ----
    stage(0, 0);
    for (int kt = 0; kt < nk; ++kt) {
      const int buf = kt & 1;
      if (kt + 1 < nk) {
        stage(kt + 1, buf ^ 1);
        asm volatile("s_waitcnt vmcnt(3)" ::: "memory");
      } else {
        asm volatile("s_waitcnt vmcnt(0)" ::: "memory");
      }
      __builtin_amdgcn_s_barrier();

      const u16* Ab = lds + buf * 4096;
      const u16* Bb = lds + BOFF + buf * 8192;
      bf16x8 af[4], bg[4];
#pragma unroll
      for (int fi = 0; fi < 4; ++fi) {
        const int row = arow0 + fi * 16;
        af[fi] = *(const bf16x8*)(Ab + row * 32 + ((kq ^ ((row >> 1) & 3)) << 3));
      }
#pragma unroll
      for (int fj = 0; fj < 4; ++fj) {
        const int row = brow0 + fj * 16;
        bg[fj] = *(const bf16x8*)(Bb + row * 32 + ((kq ^ ((row >> 1) & 3)) << 3));
      }
      asm volatile("s_waitcnt lgkmcnt(0)" ::: "memory");
      __builtin_amdgcn_sched_barrier(0);
      __builtin_amdgcn_s_setprio(1);
#pragma unroll
      for (int fi = 0; fi < 4; ++fi)
#pragma unroll
        for (int fj = 0; fj < 4; ++fj)
          acc[fi][fj] = mfma16(af[fi], bg[fj], acc[fi][fj]);
      __builtin_amdgcn_s_setprio(0);
      __builtin_amdgcn_sched_barrier(0);
      __builtin_amdgcn_s_barrier();
    }
  }

  // ---------------- epilogue: LDS-staged coalesced stores ----------------
  const int rowg = (lane >> 4) * 4;
  if constexpr (!OUTF32) {
    // full tile [128][256] u16 (64 KB): one pass
    const int seg   = FUSED ? (n0 >> 10) : 0;
    const int lcol0 = FUSED ? (n0 & 1023) : n0;
    const float* bp = b0;
    if constexpr (FUSED) bp = (seg == 0) ? b0 : (seg == 1) ? b1 : b2;
#pragma unroll
    for (int fj = 0; fj < 4; ++fj) {
      const int col = wn * 64 + fj * 16 + fr;
      const float bv = bp[lcol0 + col];
#pragma unroll
      for (int fi = 0; fi < 4; ++fi) {
#pragma unroll
        for (int rr = 0; rr < 4; ++rr) {
          const int row = wm * 64 + fi * 16 + rowg + rr;   // 0..127
          float v = acc[fi][fj][rr] + bv;
          if (FUSED && seg < 2) v = (v > 0.f) ? (v + 1.f) : __expf(v);
          lds[row * 256 + (((col >> 3) ^ ((row >> 2) & 31)) << 3) + (col & 7)] = f2bf(v);
        }
      }
    }
    __syncthreads();
    u16* outp = (u16*)out + (size_t)seg * M * 1024 + (size_t)m0 * 1024 + lcol0;
#pragma unroll
    for (int it = 0; it < 8; ++it) {
      const int g = it * 512 + t;
      const int row = g >> 5, c16 = g & 31;
      const uint4 v = *(const uint4*)&lds[row * 256 + ((c16 ^ ((row >> 2) & 31)) << 3)];
      *(uint4*)(outp + (size_t)row * 1024 + c16 * 8) = v;
    }
  } else {
    // f32: 4 passes of 32 rows through flds[32][256] (32 KB, fits 48 KB)
    float* flds = (float*)lds;
#pragma unroll
    for (int pass = 0; pass < 4; ++pass) {
      __syncthreads();
      if (wm == (pass >> 1)) {
#pragma unroll
        for (int fj = 0; fj < 4; ++fj) {
          const int col = wn * 64 + fj * 16 + fr;
          const float bv = b0[n0 + col];
#pragma unroll
          for (int f2 = 0; f2 < 2; ++f2) {
            const int fi = (pass & 1) * 2 + f2;
#pragma unroll
            for (int rr = 0; rr < 4; ++rr) {
              const int rl = f2 * 16 + rowg + rr;  // 0..31
              flds[rl * 256 + (((col >> 2) ^ ((rl >> 2) & 63)) << 2) + (col & 3)] =
                  acc[fi][fj][rr] + bv;
            }
          }
        }
      }
      __syncthreads();
#pragma unroll
      for (int it = 0; it < 4; ++it) {
        const int g = it * 512 + t;
        const int row = g >> 6, c16 = g & 63;   // rows 0..31 over 4 iters
        const uint4 v = *(const uint4*)&flds[row * 256 + ((c16 ^ ((row >> 2) & 63)) << 2)];
        *(uint4*)((float*)out + (size_t)(m0 + pass * 32 + row) * 1024 + n0 + c16 * 4) = v;
      }
    }
  }
}

// ---------------------------------------------------------------------------
// per-chunk KVT_c[e][d] = sum_i V[i][e]*K[i][d] (MFMA, coalesced uint4 out),
// Ks_c[d] = sum_i K[i][d] (f32).  grid (NCC, H, B), 256 threads (4 waves).
// ---------------------------------------------------------------------------
__global__ __launch_bounds__(256) void chunk_kv_k(const u16* __restrict__ Kb,
                                                  const u16* __restrict__ Vb,
                                                  u16* __restrict__ KVTc,
                                                  float* __restrict__ Ksc) {
  const int c = blockIdx.x, h = blockIdx.y, b = blockIdx.z;
  __shared__ u16 KT[64][72], VT[64][72];   // transposed: [d][i] / [e][i]
  const int t = threadIdx.x, lane = t & 63, w = t >> 6;
  {
    const int i = t >> 2, c0 = (t & 3) * 16;
    const size_t g = ((size_t)(b * Ss + c * CC + i)) * 1024 + h * 64 + c0;
    const u16* kp = Kb + g;
    const u16* vp = Vb + g;
#pragma unroll
    for (int j = 0; j < 16; ++j) { KT[c0 + j][i] = kp[j]; VT[c0 + j][i] = vp[j]; }
  }
  __syncthreads();
  f32x4 acc[4];
#pragma unroll
  for (int j = 0; j < 4; ++j) acc[j] = f32x4{0.f, 0.f, 0.f, 0.f};
  const int fr = lane & 15, kq = (lane >> 4) * 8;
#pragma unroll
  for (int kk = 0; kk < 2; ++kk) {
    const bf16x8 av = *(const bf16x8*)&VT[w * 16 + fr][kk * 32 + kq];
#pragma unroll
    for (int fj = 0; fj < 4; ++fj) {
      const bf16x8 bk = *(const bf16x8*)&KT[fj * 16 + fr][kk * 32 + kq];
      acc[fj] = mfma16(av, bk, acc[fj]);
    }
  }
  float ksv = 0.f;
  if (t < 64) {
#pragma unroll
    for (int ii = 0; ii < 8; ++ii) {
      const bf16x8 kv = *(const bf16x8*)&KT[t][ii * 8];
#pragma unroll
      for (int j = 0; j < 8; ++j) ksv += bf2f((u16)kv[j]);
    }
  }
  __syncthreads();
#pragma unroll
  for (int fj = 0; fj < 4; ++fj)
#pragma unroll
    for (int rr = 0; rr < 4; ++rr)
      VT[w * 16 + (lane >> 4) * 4 + rr][fj * 16 + fr] = f2bf(acc[fj][rr]);
  __syncthreads();
  const size_t base = ((size_t)((b * Hh + h) * NCC + c)) * 4096;
  {
    const int row = t >> 2, q8 = (t & 3) * 8;
    *(uint4*)(KVTc + base + (size_t)row * 64 + q8)      = *(const uint4*)&VT[row][q8];
    *(uint4*)(KVTc + base + (size_t)row * 64 + q8 + 32) = *(const uint4*)&VT[row][q8 + 32];
  }
  if (t < 64) Ksc[((size_t)((b * Hh + h) * NCC + c)) * 64 + t] = ksv;
}

// ---------------------------------------------------------------------------
// exclusive prefix over chunks per (b,h).  grid (64, 4); 8-deep ring buffer.
// ---------------------------------------------------------------------------
__global__ __launch_bounds__(256) void prefix_k(const u16* __restrict__ KVTc,
                                                const float* __restrict__ Ksc,
                                                u16* __restrict__ KVpreT,
                                                float* __restrict__ Kspre) {
  const int bh = blockIdx.x, eg = blockIdx.y;
  const int t = threadIdx.x;
  const int e4 = eg * 1024 + t * 4;
  const u16* src = KVTc + (size_t)bh * NCC * 4096 + e4;
  u16* dst = KVpreT + (size_t)bh * NCC * 4096 + e4;
  const float* kss = Ksc + (size_t)bh * NCC * 64 + t;
  float* ksd = Kspre + (size_t)bh * NCC * 64 + t;
  const bool dok = (eg == 0 && t < 64);

  uint2 buf[8];
  float kbuf[8];
#pragma unroll
  for (int j = 0; j < 8; ++j) {
    buf[j] = *(const uint2*)(src + (size_t)j * 4096);
    kbuf[j] = dok ? kss[(size_t)j * 64] : 0.f;
  }
  float run[4] = {0.f, 0.f, 0.f, 0.f};
  float rk = 0.f;
  for (int g = 0; g < 8; ++g) {
#pragma unroll
    for (int j = 0; j < 8; ++j) {
      const int c = g * 8 + j;
      union { uint2 v; u16 s[4]; } in, ov;
      in.v = buf[j];
      const float kin = kbuf[j];
      if (c + 8 < NCC) {
        buf[j] = *(const uint2*)(src + (size_t)(c + 8) * 4096);
        if (dok) kbuf[j] = kss[(size_t)(c + 8) * 64];
      }
#pragma unroll
      for (int k = 0; k < 4; ++k) { ov.s[k] = f2bf(run[k]); run[k] += bf2f(in.s[k]); }
      *(uint2*)(dst + (size_t)c * 4096) = ov.v;
      if (dok) { ksd[(size_t)c * 64] = rk; rk += kin; }
    }
  }
}

// ---------------------------------------------------------------------------
// per-(b,h,c) chunk output.  grid (NCC, H, B), 256 threads (4 waves).
// ---------------------------------------------------------------------------
__global__ __launch_bounds__(256) void chunk_out_k(const u16* __restrict__ Qb,
                                                   const u16* __restrict__ Kb,
                                                   const u16* __restrict__ Vb,
                                                   const u16* __restrict__ KVpreT,
                                                   const float* __restrict__ Kspre,
                                                   u16* __restrict__ attn) {
  const int c = blockIdx.x, h = blockIdx.y, b = blockIdx.z;
  const int bh = b * Hh + h;
  __shared__ u16 Ql[64][72], Kl[64][72], VT[64][72], Pl[64][72];
  __shared__ float den[64];
  const int t = threadIdx.x, lane = t & 63, w = t >> 6;

  {
    const int i = t >> 2, c0 = (t & 3) * 16;
    const size_t g = ((size_t)(b * Ss + c * CC + i)) * 1024 + h * 64 + c0;
    const uint4* qp = (const uint4*)(Qb + g);
    uint4* qd = (uint4*)&Ql[i][c0]; qd[0] = qp[0]; qd[1] = qp[1];
    const uint4* kp = (const uint4*)(Kb + g);
    uint4* kd = (uint4*)&Kl[i][c0]; kd[0] = kp[0]; kd[1] = kp[1];
    const u16* vp = Vb + g;
#pragma unroll
    for (int j = 0; j < 16; ++j) VT[c0 + j][i] = vp[j];  // transpose V -> [e][i]
  }
  __syncthreads();

  f32x4 sacc[4];
#pragma unroll
  for (int fj = 0; fj < 4; ++fj) sacc[fj] = f32x4{0.f, 0.f, 0.f, 0.f};
#pragma unroll
  for (int kd = 0; kd < 2; ++kd) {
    const bf16x8 aq = *(const bf16x8*)&Ql[w * 16 + (lane & 15)][kd * 32 + (lane >> 4) * 8];
#pragma unroll
    for (int fj = 0; fj < 4; ++fj) {
      const bf16x8 bk = *(const bf16x8*)&Kl[fj * 16 + (lane & 15)][kd * 32 + (lane >> 4) * 8];
      sacc[fj] = mfma16(aq, bk, sacc[fj]);
    }
  }
  float rowsum[4] = {0.f, 0.f, 0.f, 0.f};
#pragma unroll
  for (int fj = 0; fj < 4; ++fj) {
#pragma unroll
    for (int rr = 0; rr < 4; ++rr) {
      const int i_loc = w * 16 + (lane >> 4) * 4 + rr;
      const int j_loc = fj * 16 + (lane & 15);
      const float v = (j_loc <= i_loc) ? sacc[fj][rr] : 0.f;
      Pl[i_loc][j_loc] = f2bf(v);
      rowsum[rr] += v;
    }
  }
#pragma unroll
  for (int off = 1; off < 16; off <<= 1) {
#pragma unroll
    for (int rr = 0; rr < 4; ++rr) rowsum[rr] += __shfl_xor(rowsum[rr], off, 64);
  }
  if ((lane & 15) == 0) {
#pragma unroll
    for (int rr = 0; rr < 4; ++rr) den[w * 16 + (lane >> 4) * 4 + rr] = rowsum[rr];
  }
  __syncthreads();
  {
    const int i = t >> 2, part = t & 3;
    const float* ksp = Kspre + ((size_t)(bh * NCC + c)) * 64 + part * 16;
    float s = 0.f;
#pragma unroll
    for (int sg = 0; sg < 2; ++sg) {
      const bf16x8 q = *(const bf16x8*)&Ql[i][part * 16 + sg * 8];
#pragma unroll
      for (int j = 0; j < 8; ++j) s += bf2f((u16)q[j]) * ksp[sg * 8 + j];
    }
    s += __shfl_xor(s, 1, 64);
    s += __shfl_xor(s, 2, 64);
    if (part == 0) den[i] = den[i] + s + 1e-6f;
  }
  __syncthreads();

  f32x4 oacc[4];
#pragma unroll
  for (int fj = 0; fj < 4; ++fj) oacc[fj] = f32x4{0.f, 0.f, 0.f, 0.f};
  const u16* kvb = KVpreT + ((size_t)(bh * NCC + c)) * 4096;
#pragma unroll
  for (int ks2 = 0; ks2 < 2; ++ks2) {
    const bf16x8 aq = *(const bf16x8*)&Ql[w * 16 + (lane & 15)][ks2 * 32 + (lane >> 4) * 8];
#pragma unroll
    for (int fj = 0; fj < 4; ++fj) {
      const bf16x8 bv =
          *(const bf16x8*)(kvb + (size_t)(fj * 16 + (lane & 15)) * 64 + ks2 * 32 + (lane >> 4) * 8);
      oacc[fj] = mfma16(aq, bv, oacc[fj]);
    }
  }
#pragma unroll
  for (int ks3 = 0; ks3 < 2; ++ks3) {
    const bf16x8 ap = *(const bf16x8*)&Pl[w * 16 + (lane & 15)][ks3 * 32 + (lane >> 4) * 8];
#pragma unroll
    for (int fj = 0; fj < 4; ++fj) {
      const bf16x8 bv = *(const bf16x8*)&VT[fj * 16 + (lane & 15)][ks3 * 32 + (lane >> 4) * 8];
      oacc[fj] = mfma16(ap, bv, oacc[fj]);
    }
  }
  __syncthreads();
#pragma unroll
  for (int fj = 0; fj < 4; ++fj) {
#pragma unroll
    for (int rr = 0; rr < 4; ++rr) {
      const int i_loc = w * 16 + (lane >> 4) * 4 + rr;
      Pl[i_loc][fj * 16 + (lane & 15)] = f2bf(oacc[fj][rr] / den[i_loc]);
    }
  }
  __syncthreads();
  {
    const int row = t >> 2, q8 = (t & 3) * 8;
    u16* ap2 = attn + ((size_t)(b * Ss + c * CC + row)) * 1024 + h * 64;
    *(uint4*)(ap2 + q8)      = *(const uint4*)&Pl[row][q8];
    *(uint4*)(ap2 + q8 + 32) = *(const uint4*)&Pl[row][q8 + 32];
  }
}

// ---------------------------------------------------------------------------
extern "C" void kernel_launch(void* const* d_in, const int* in_sizes, int n_in,
                              void* d_out, int out_size, void* d_ws, size_t ws_size,
                              hipStream_t stream) {
  (void)in_sizes; (void)n_in; (void)out_size; (void)ws_size;
  const float* x  = (const float*)d_in[0];
  const float* Wq = (const float*)d_in[1];
  const float* bq = (const float*)d_in[2];
  const float* Wk = (const float*)d_in[3];
  const float* bk = (const float*)d_in[4];
  const float* Wv = (const float*)d_in[5];
  const float* bv = (const float*)d_in[6];
  const float* Wo = (const float*)d_in[7];
  const float* bo = (const float*)d_in[8];
  float* out = (float*)d_out;
  char* ws = (char*)d_ws;

  size_t off = 0;
  auto take = [&](size_t bytes) { size_t r = off; off += (bytes + 255) & ~(size_t)255; return r; };
  const size_t WQKV_B = (size_t)3072 * 1024 * 2;        // 6 MB
  const size_t WT_B   = (size_t)1024 * 1024 * 2;        // 2 MB
  const size_t BIG_B  = (size_t)16384 * 1024 * 2;       // 32 MB
  const size_t KVT_B  = (size_t)64 * NCC * 4096 * 2;    // 32 MB bf16
  const size_t KS_B   = (size_t)64 * NCC * 64 * 4;      // 1 MB f32

  u16* WqkvT  = (u16*)(ws + take(WQKV_B));
  u16* WoT    = (u16*)(ws + take(WT_B));
  size_t shared_off = take(BIG_B);                      // xbf -> KVTc -> attn alias chain
  u16* xbf    = (u16*)(ws + shared_off);
  u16* KVTc   = (u16*)(ws + shared_off);
  u16* attn   = (u16*)(ws + shared_off);
  u16* Qb     = (u16*)(ws + take(BIG_B));               // Q|K|V contiguous (3 x 32 MB)
  u16* Kb     = (u16*)(ws + take(BIG_B));
  u16* Vb     = (u16*)(ws + take(BIG_B));
  u16* KVpreT = (u16*)(ws + take(KVT_B));
  float* Ksc  = (float*)(ws + take(KS_B));
  float* Kspre= (float*)(ws + take(KS_B));

  const dim3 blk(256);
  prep_k<<<dim3(12288), blk, 0, stream>>>(x, Wq, Wk, Wv, Wo, xbf, WqkvT, WoT);

  // fused QKV: N=3072 -> Qb/Kb/Vb; grid (N/256, M/128) = (12, 128) = 1536 wg
  gemm128_k<true, false, false><<<dim3(12, 128), dim3(512), 0, stream>>>(
      xbf, WqkvT, bq, bk, bv, Qb, 16384, 1024);

  const dim3 gC(NCC, Hh, 4);
  chunk_kv_k<<<gC, blk, 0, stream>>>(Kb, Vb, KVTc, Ksc);   // KVTc reuses xbf slot
  prefix_k<<<dim3(64, 4), blk, 0, stream>>>(KVTc, Ksc, KVpreT, Kspre);
  chunk_out_k<<<gC, blk, 0, stream>>>(Qb, Kb, Vb, KVpreT, Kspre, attn);

  // Wo: grid (1024/256, 16384/128) = (4, 128) = 512 wg, occupancy-3 variant
  gemm128_k<false, true, true><<<dim3(4, 128), dim3(512), 0, stream>>>(
      attn, WoT, bo, NULL, NULL, out, 16384, 1024);
}

// Round 14
// 256.198 us; speedup vs baseline: 1.8422x; 1.8422x over previous
//
#include <hip/hip_runtime.h>
#include <stdint.h>

// ---------------------------------------------------------------------------
// LinearAttention (B=4, S=4096, HID=1024, H=16, D=64), chunked formulation.
// Round 14: REVERT to round-12 configuration (session best: 256.4 us).
// R13's occupancy-3 Wo variant spilled (launch_bounds(512,6) capped VGPR at
// ~80 < ~100 needed -> 1 GB scratch traffic, Wo 41->272 us).  Both GEMM
// instances use the R12 loop: 128x256, BK=32, triple-buffered 72 KB LDS,
// 2-tile lookahead, 1 barrier/tile, vmcnt(3) gate, T2 swizzle, T5 setprio,
// XCD swizzle, occupancy-2.  Middle kernels unchanged.
// ---------------------------------------------------------------------------

#define DEVI __device__ __forceinline__

typedef __attribute__((ext_vector_type(8))) short bf16x8;
typedef __attribute__((ext_vector_type(4))) float f32x4;
typedef unsigned short u16;

DEVI u16 f2bf(float f) {
  union { float f; uint32_t u; } x; x.f = f;
  return (u16)((x.u + 0x7FFFu + ((x.u >> 16) & 1u)) >> 16);  // RNE
}
DEVI float bf2f(u16 u) {
  union { uint32_t u; float f; } x; x.u = ((uint32_t)u) << 16;
  return x.f;
}
DEVI f32x4 mfma16(bf16x8 a, bf16x8 b, f32x4 c) {
  return __builtin_amdgcn_mfma_f32_16x16x32_bf16(a, b, c, 0, 0, 0);
}

typedef __attribute__((address_space(3))) void* lds_vp;
typedef const __attribute__((address_space(1))) void* glb_vp;
DEVI void gload_lds16(const void* g, void* l) {
  __builtin_amdgcn_global_load_lds((glb_vp)g, (lds_vp)l, 16, 0, 0);
}

static constexpr int Ss  = 4096;
static constexpr int Hh  = 16;
static constexpr int CC  = 64;          // chunk length
static constexpr int NCC = Ss / CC;     // 64 chunks

// ---------------------------------------------------------------------------
// prep: x (fp32)->bf16 (blocks 0..8191) and 4 weight transposes+cvt
// ---------------------------------------------------------------------------
__global__ __launch_bounds__(256) void prep_k(const float* __restrict__ x,
                                              const float* __restrict__ w0,
                                              const float* __restrict__ w1,
                                              const float* __restrict__ w2,
                                              const float* __restrict__ w3,
                                              u16* __restrict__ xbf,
                                              u16* __restrict__ dqkv,
                                              u16* __restrict__ dwo) {
  __shared__ float tl[32][33];
  const int bid = blockIdx.x;
  if (bid < 8192) {
    const int i = bid * 256 + threadIdx.x;
    const float4* p = (const float4*)(x + (size_t)i * 8);
    const float4 a = p[0], b = p[1];
    union { uint4 v; u16 s[8]; } u;
    u.s[0] = f2bf(a.x); u.s[1] = f2bf(a.y); u.s[2] = f2bf(a.z); u.s[3] = f2bf(a.w);
    u.s[4] = f2bf(b.x); u.s[5] = f2bf(b.y); u.s[6] = f2bf(b.z); u.s[7] = f2bf(b.w);
    ((uint4*)xbf)[i] = u.v;
    return;
  }
  const int wz = bid - 8192;
  const int z = wz >> 10, wl = wz & 1023;
  const int bx = wl & 31, by = wl >> 5;
  const float* in = (z == 0) ? w0 : (z == 1) ? w1 : (z == 2) ? w2 : w3;
  u16* out = (z < 3) ? (dqkv + (size_t)z * 1024 * 1024) : dwo;
  const int tx = threadIdx.x & 31, ty = threadIdx.x >> 5;
#pragma unroll
  for (int j = 0; j < 4; ++j)
    tl[ty + j * 8][tx] = in[(size_t)(by * 32 + ty + j * 8) * 1024 + bx * 32 + tx];
  __syncthreads();
#pragma unroll
  for (int j = 0; j < 4; ++j)
    out[(size_t)(bx * 32 + ty + j * 8) * 1024 + by * 32 + tx] = f2bf(tl[tx][ty + j * 8]);
}

// ---------------------------------------------------------------------------
// 128x256 GEMM, BK=32, TRIPLE-buffered staging (72 KB LDS), 512 threads =
// 8 waves (2M x 4N), per-wave out 64x64, acc[4][4].  2 blocks/CU.
// Per tile t:  vmcnt(3) gate (t's loads, issued at t-2, must land) ->
// s_barrier -> stage(t+2) -> 8 ds_read(swz) -> lgkm0 -> setprio + 16 MFMA.
// ONE barrier per tile; loads always ~2 tiles ahead.
// ---------------------------------------------------------------------------
template <bool FUSED, bool OUTF32>
__global__ __launch_bounds__(512, 4) void gemm128_k(const u16* __restrict__ A,
                                                    const u16* __restrict__ BT,
                                                    const float* __restrict__ b0,
                                                    const float* __restrict__ b1,
                                                    const float* __restrict__ b2,
                                                    void* __restrict__ out,
                                                    int M, int K) {
  __shared__ __attribute__((aligned(16))) u16 lds[36864];  // 72 KiB
  const int t = threadIdx.x, lane = t & 63, w = t >> 6;
  const int wm = w >> 2, wn = w & 3;   // 2M x 4N over 128x256

  // XCD-aware bijective swizzle (nwg % 8 == 0 for our grids)
  const int nx = gridDim.x;
  const int nwg = nx * gridDim.y;
  const int bid = blockIdx.y * nx + blockIdx.x;
  const int swz = (bid & 7) * (nwg >> 3) + (bid >> 3);
  const int bx = swz % nx, by = swz / nx;
  const int m0 = by * 128, n0 = bx * 256;

  const u16* gA = A + (size_t)m0 * K;
  const u16* gB = BT + (size_t)n0 * K;

  // staging: A slot [128][32] (8 KB, bufs at 0/4096/8192 u16); B slot
  // [256][32] (16 KB, bufs at 12288 + b*8192).  Global k-chunk pre-XOR-
  // swizzled (both-sides-or-neither, rule #21).
  const int sr = t >> 2;
  const int sc = (t & 3) ^ ((sr >> 1) & 3);
  auto stage = [&](int kt2, int buf) {
    const int kof = kt2 << 5;
    gload_lds16(gA + (size_t)sr * K + kof + sc * 8, lds + buf * 4096 + t * 8);
    gload_lds16(gB + (size_t)sr * K + kof + sc * 8, lds + 12288 + buf * 8192 + t * 8);
    gload_lds16(gB + (size_t)(sr + 128) * K + kof + sc * 8,
                lds + 12288 + buf * 8192 + 4096 + t * 8);
  };

  f32x4 acc[4][4];
#pragma unroll
  for (int i = 0; i < 4; ++i)
#pragma unroll
    for (int j = 0; j < 4; ++j) acc[i][j] = f32x4{0.f, 0.f, 0.f, 0.f};

  // prologue: tiles 0,1 -> bufs 0,1 (6 loads in flight)
  stage(0, 0);
  stage(1, 1);

  const int fr = lane & 15, kq = lane >> 4;
  const int arow0 = wm * 64 + fr;
  const int brow0 = wn * 64 + fr;

  const int nk = K >> 5;
  int cb = 0, nb = 2;   // current buf, stage-target buf ((kt+2)%3)
  for (int kt = 0; kt < nk; ++kt) {
    if (kt + 1 < nk) asm volatile("s_waitcnt vmcnt(3)" ::: "memory");
    else             asm volatile("s_waitcnt vmcnt(0)" ::: "memory");
    __builtin_amdgcn_s_barrier();
    if (kt + 2 < nk) stage(kt + 2, nb);

    const u16* Ab = lds + cb * 4096;
    const u16* Bb = lds + 12288 + cb * 8192;
    bf16x8 af[4], bg[4];
#pragma unroll
    for (int fi = 0; fi < 4; ++fi) {
      const int row = arow0 + fi * 16;
      af[fi] = *(const bf16x8*)(Ab + row * 32 + ((kq ^ ((row >> 1) & 3)) << 3));
    }
#pragma unroll
    for (int fj = 0; fj < 4; ++fj) {
      const int row = brow0 + fj * 16;
      bg[fj] = *(const bf16x8*)(Bb + row * 32 + ((kq ^ ((row >> 1) & 3)) << 3));
    }
    asm volatile("s_waitcnt lgkmcnt(0)" ::: "memory");
    __builtin_amdgcn_sched_barrier(0);
    __builtin_amdgcn_s_setprio(1);
#pragma unroll
    for (int fi = 0; fi < 4; ++fi)
#pragma unroll
      for (int fj = 0; fj < 4; ++fj)
        acc[fi][fj] = mfma16(af[fi], bg[fj], acc[fi][fj]);
    __builtin_amdgcn_s_setprio(0);
    __builtin_amdgcn_sched_barrier(0);

    cb = (cb + 1 == 3) ? 0 : cb + 1;
    nb = (nb + 1 == 3) ? 0 : nb + 1;
  }
  __syncthreads();   // all waves' reads retired before LDS is repurposed

  // ---------------- epilogue: LDS-staged coalesced stores ----------------
  const int rowg = (lane >> 4) * 4;
  if constexpr (!OUTF32) {
    // full tile [128][256] u16 fits: one pass
    const int seg   = FUSED ? (n0 >> 10) : 0;
    const int lcol0 = FUSED ? (n0 & 1023) : n0;
    const float* bp = b0;
    if constexpr (FUSED) bp = (seg == 0) ? b0 : (seg == 1) ? b1 : b2;
#pragma unroll
    for (int fj = 0; fj < 4; ++fj) {
      const int col = wn * 64 + fj * 16 + fr;
      const float bv = bp[lcol0 + col];
#pragma unroll
      for (int fi = 0; fi < 4; ++fi) {
#pragma unroll
        for (int rr = 0; rr < 4; ++rr) {
          const int row = wm * 64 + fi * 16 + rowg + rr;   // 0..127
          float v = acc[fi][fj][rr] + bv;
          if (FUSED && seg < 2) v = (v > 0.f) ? (v + 1.f) : __expf(v);
          lds[row * 256 + (((col >> 3) ^ ((row >> 2) & 31)) << 3) + (col & 7)] = f2bf(v);
        }
      }
    }
    __syncthreads();
    u16* outp = (u16*)out + (size_t)seg * M * 1024 + (size_t)m0 * 1024 + lcol0;
#pragma unroll
    for (int it = 0; it < 8; ++it) {
      const int g = it * 512 + t;
      const int row = g >> 5, c16 = g & 31;
      const uint4 v = *(const uint4*)&lds[row * 256 + ((c16 ^ ((row >> 2) & 31)) << 3)];
      *(uint4*)(outp + (size_t)row * 1024 + c16 * 8) = v;
    }
  } else {
    // f32: two passes of 64 rows through flds[64][256] (64 KB)
    float* flds = (float*)lds;
#pragma unroll
    for (int pass = 0; pass < 2; ++pass) {
      __syncthreads();
      if (wm == pass) {
#pragma unroll
        for (int fj = 0; fj < 4; ++fj) {
          const int col = wn * 64 + fj * 16 + fr;
          const float bv = b0[n0 + col];
#pragma unroll
          for (int fi = 0; fi < 4; ++fi) {
#pragma unroll
            for (int rr = 0; rr < 4; ++rr) {
              const int rl = fi * 16 + rowg + rr;  // 0..63
              flds[rl * 256 + (((col >> 2) ^ ((rl >> 2) & 63)) << 2) + (col & 3)] =
                  acc[fi][fj][rr] + bv;
            }
          }
        }
      }
      __syncthreads();
#pragma unroll
      for (int it = 0; it < 8; ++it) {
        const int g = it * 512 + t;
        const int row = g >> 6, c16 = g & 63;
        const uint4 v = *(const uint4*)&flds[row * 256 + ((c16 ^ ((row >> 2) & 63)) << 2)];
        *(uint4*)((float*)out + (size_t)(m0 + pass * 64 + row) * 1024 + n0 + c16 * 4) = v;
      }
    }
  }
}

// ---------------------------------------------------------------------------
// per-chunk KVT_c[e][d] = sum_i V[i][e]*K[i][d] (MFMA, coalesced uint4 out),
// Ks_c[d] = sum_i K[i][d] (f32).  grid (NCC, H, B), 256 threads (4 waves).
// ---------------------------------------------------------------------------
__global__ __launch_bounds__(256) void chunk_kv_k(const u16* __restrict__ Kb,
                                                  const u16* __restrict__ Vb,
                                                  u16* __restrict__ KVTc,
                                                  float* __restrict__ Ksc) {
  const int c = blockIdx.x, h = blockIdx.y, b = blockIdx.z;
  __shared__ u16 KT[64][72], VT[64][72];   // transposed: [d][i] / [e][i]
  const int t = threadIdx.x, lane = t & 63, w = t >> 6;
  {
    const int i = t >> 2, c0 = (t & 3) * 16;
    const size_t g = ((size_t)(b * Ss + c * CC + i)) * 1024 + h * 64 + c0;
    const u16* kp = Kb + g;
    const u16* vp = Vb + g;
#pragma unroll
    for (int j = 0; j < 16; ++j) { KT[c0 + j][i] = kp[j]; VT[c0 + j][i] = vp[j]; }
  }
  __syncthreads();
  f32x4 acc[4];
#pragma unroll
  for (int j = 0; j < 4; ++j) acc[j] = f32x4{0.f, 0.f, 0.f, 0.f};
  const int fr = lane & 15, kq = (lane >> 4) * 8;
#pragma unroll
  for (int kk = 0; kk < 2; ++kk) {
    const bf16x8 av = *(const bf16x8*)&VT[w * 16 + fr][kk * 32 + kq];
#pragma unroll
    for (int fj = 0; fj < 4; ++fj) {
      const bf16x8 bk = *(const bf16x8*)&KT[fj * 16 + fr][kk * 32 + kq];
      acc[fj] = mfma16(av, bk, acc[fj]);
    }
  }
  float ksv = 0.f;
  if (t < 64) {
#pragma unroll
    for (int ii = 0; ii < 8; ++ii) {
      const bf16x8 kv = *(const bf16x8*)&KT[t][ii * 8];
#pragma unroll
      for (int j = 0; j < 8; ++j) ksv += bf2f((u16)kv[j]);
    }
  }
  __syncthreads();
#pragma unroll
  for (int fj = 0; fj < 4; ++fj)
#pragma unroll
    for (int rr = 0; rr < 4; ++rr)
      VT[w * 16 + (lane >> 4) * 4 + rr][fj * 16 + fr] = f2bf(acc[fj][rr]);
  __syncthreads();
  const size_t base = ((size_t)((b * Hh + h) * NCC + c)) * 4096;
  {
    const int row = t >> 2, q8 = (t & 3) * 8;
    *(uint4*)(KVTc + base + (size_t)row * 64 + q8)      = *(const uint4*)&VT[row][q8];
    *(uint4*)(KVTc + base + (size_t)row * 64 + q8 + 32) = *(const uint4*)&VT[row][q8 + 32];
  }
  if (t < 64) Ksc[((size_t)((b * Hh + h) * NCC + c)) * 64 + t] = ksv;
}

// ---------------------------------------------------------------------------
// exclusive prefix over chunks per (b,h).  grid (64, 4); 8-deep ring buffer.
// ---------------------------------------------------------------------------
__global__ __launch_bounds__(256) void prefix_k(const u16* __restrict__ KVTc,
                                                const float* __restrict__ Ksc,
                                                u16* __restrict__ KVpreT,
                                                float* __restrict__ Kspre) {
  const int bh = blockIdx.x, eg = blockIdx.y;
  const int t = threadIdx.x;
  const int e4 = eg * 1024 + t * 4;
  const u16* src = KVTc + (size_t)bh * NCC * 4096 + e4;
  u16* dst = KVpreT + (size_t)bh * NCC * 4096 + e4;
  const float* kss = Ksc + (size_t)bh * NCC * 64 + t;
  float* ksd = Kspre + (size_t)bh * NCC * 64 + t;
  const bool dok = (eg == 0 && t < 64);

  uint2 buf[8];
  float kbuf[8];
#pragma unroll
  for (int j = 0; j < 8; ++j) {
    buf[j] = *(const uint2*)(src + (size_t)j * 4096);
    kbuf[j] = dok ? kss[(size_t)j * 64] : 0.f;
  }
  float run[4] = {0.f, 0.f, 0.f, 0.f};
  float rk = 0.f;
  for (int g = 0; g < 8; ++g) {
#pragma unroll
    for (int j = 0; j < 8; ++j) {
      const int c = g * 8 + j;
      union { uint2 v; u16 s[4]; } in, ov;
      in.v = buf[j];
      const float kin = kbuf[j];
      if (c + 8 < NCC) {
        buf[j] = *(const uint2*)(src + (size_t)(c + 8) * 4096);
        if (dok) kbuf[j] = kss[(size_t)(c + 8) * 64];
      }
#pragma unroll
      for (int k = 0; k < 4; ++k) { ov.s[k] = f2bf(run[k]); run[k] += bf2f(in.s[k]); }
      *(uint2*)(dst + (size_t)c * 4096) = ov.v;
      if (dok) { ksd[(size_t)c * 64] = rk; rk += kin; }
    }
  }
}

// ---------------------------------------------------------------------------
// per-(b,h,c) chunk output.  grid (NCC, H, B), 256 threads (4 waves).
// ---------------------------------------------------------------------------
__global__ __launch_bounds__(256) void chunk_out_k(const u16* __restrict__ Qb,
                                                   const u16* __restrict__ Kb,
                                                   const u16* __restrict__ Vb,
                                                   const u16* __restrict__ KVpreT,
                                                   const float* __restrict__ Kspre,
                                                   u16* __restrict__ attn) {
  const int c = blockIdx.x, h = blockIdx.y, b = blockIdx.z;
  const int bh = b * Hh + h;
  __shared__ u16 Ql[64][72], Kl[64][72], VT[64][72], Pl[64][72];
  __shared__ float den[64];
  const int t = threadIdx.x, lane = t & 63, w = t >> 6;

  {
    const int i = t >> 2, c0 = (t & 3) * 16;
    const size_t g = ((size_t)(b * Ss + c * CC + i)) * 1024 + h * 64 + c0;
    const uint4* qp = (const uint4*)(Qb + g);
    uint4* qd = (uint4*)&Ql[i][c0]; qd[0] = qp[0]; qd[1] = qp[1];
    const uint4* kp = (const uint4*)(Kb + g);
    uint4* kd = (uint4*)&Kl[i][c0]; kd[0] = kp[0]; kd[1] = kp[1];
    const u16* vp = Vb + g;
#pragma unroll
    for (int j = 0; j < 16; ++j) VT[c0 + j][i] = vp[j];  // transpose V -> [e][i]
  }
  __syncthreads();

  f32x4 sacc[4];
#pragma unroll
  for (int fj = 0; fj < 4; ++fj) sacc[fj] = f32x4{0.f, 0.f, 0.f, 0.f};
#pragma unroll
  for (int kd = 0; kd < 2; ++kd) {
    const bf16x8 aq = *(const bf16x8*)&Ql[w * 16 + (lane & 15)][kd * 32 + (lane >> 4) * 8];
#pragma unroll
    for (int fj = 0; fj < 4; ++fj) {
      const bf16x8 bk = *(const bf16x8*)&Kl[fj * 16 + (lane & 15)][kd * 32 + (lane >> 4) * 8];
      sacc[fj] = mfma16(aq, bk, sacc[fj]);
    }
  }
  float rowsum[4] = {0.f, 0.f, 0.f, 0.f};
#pragma unroll
  for (int fj = 0; fj < 4; ++fj) {
#pragma unroll
    for (int rr = 0; rr < 4; ++rr) {
      const int i_loc = w * 16 + (lane >> 4) * 4 + rr;
      const int j_loc = fj * 16 + (lane & 15);
      const float v = (j_loc <= i_loc) ? sacc[fj][rr] : 0.f;
      Pl[i_loc][j_loc] = f2bf(v);
      rowsum[rr] += v;
    }
  }
#pragma unroll
  for (int off = 1; off < 16; off <<= 1) {
#pragma unroll
    for (int rr = 0; rr < 4; ++rr) rowsum[rr] += __shfl_xor(rowsum[rr], off, 64);
  }
  if ((lane & 15) == 0) {
#pragma unroll
    for (int rr = 0; rr < 4; ++rr) den[w * 16 + (lane >> 4) * 4 + rr] = rowsum[rr];
  }
  __syncthreads();
  {
    const int i = t >> 2, part = t & 3;
    const float* ksp = Kspre + ((size_t)(bh * NCC + c)) * 64 + part * 16;
    float s = 0.f;
#pragma unroll
    for (int sg = 0; sg < 2; ++sg) {
      const bf16x8 q = *(const bf16x8*)&Ql[i][part * 16 + sg * 8];
#pragma unroll
      for (int j = 0; j < 8; ++j) s += bf2f((u16)q[j]) * ksp[sg * 8 + j];
    }
    s += __shfl_xor(s, 1, 64);
    s += __shfl_xor(s, 2, 64);
    if (part == 0) den[i] = den[i] + s + 1e-6f;
  }
  __syncthreads();

  f32x4 oacc[4];
#pragma unroll
  for (int fj = 0; fj < 4; ++fj) oacc[fj] = f32x4{0.f, 0.f, 0.f, 0.f};
  const u16* kvb = KVpreT + ((size_t)(bh * NCC + c)) * 4096;
#pragma unroll
  for (int ks2 = 0; ks2 < 2; ++ks2) {
    const bf16x8 aq = *(const bf16x8*)&Ql[w * 16 + (lane & 15)][ks2 * 32 + (lane >> 4) * 8];
#pragma unroll
    for (int fj = 0; fj < 4; ++fj) {
      const bf16x8 bv =
          *(const bf16x8*)(kvb + (size_t)(fj * 16 + (lane & 15)) * 64 + ks2 * 32 + (lane >> 4) * 8);
      oacc[fj] = mfma16(aq, bv, oacc[fj]);
    }
  }
#pragma unroll
  for (int ks3 = 0; ks3 < 2; ++ks3) {
    const bf16x8 ap = *(const bf16x8*)&Pl[w * 16 + (lane & 15)][ks3 * 32 + (lane >> 4) * 8];
#pragma unroll
    for (int fj = 0; fj < 4; ++fj) {
      const bf16x8 bv = *(const bf16x8*)&VT[fj * 16 + (lane & 15)][ks3 * 32 + (lane >> 4) * 8];
      oacc[fj] = mfma16(ap, bv, oacc[fj]);
    }
  }
  __syncthreads();
#pragma unroll
  for (int fj = 0; fj < 4; ++fj) {
#pragma unroll
    for (int rr = 0; rr < 4; ++rr) {
      const int i_loc = w * 16 + (lane >> 4) * 4 + rr;
      Pl[i_loc][fj * 16 + (lane & 15)] = f2bf(oacc[fj][rr] / den[i_loc]);
    }
  }
  __syncthreads();
  {
    const int row = t >> 2, q8 = (t & 3) * 8;
    u16* ap2 = attn + ((size_t)(b * Ss + c * CC + row)) * 1024 + h * 64;
    *(uint4*)(ap2 + q8)      = *(const uint4*)&Pl[row][q8];
    *(uint4*)(ap2 + q8 + 32) = *(const uint4*)&Pl[row][q8 + 32];
  }
}

// ---------------------------------------------------------------------------
extern "C" void kernel_launch(void* const* d_in, const int* in_sizes, int n_in,
                              void* d_out, int out_size, void* d_ws, size_t ws_size,
                              hipStream_t stream) {
  (void)in_sizes; (void)n_in; (void)out_size; (void)ws_size;
  const float* x  = (const float*)d_in[0];
  const float* Wq = (const float*)d_in[1];
  const float* bq = (const float*)d_in[2];
  const float* Wk = (const float*)d_in[3];
  const float* bk = (const float*)d_in[4];
  const float* Wv = (const float*)d_in[5];
  const float* bv = (const float*)d_in[6];
  const float* Wo = (const float*)d_in[7];
  const float* bo = (const float*)d_in[8];
  float* out = (float*)d_out;
  char* ws = (char*)d_ws;

  size_t off = 0;
  auto take = [&](size_t bytes) { size_t r = off; off += (bytes + 255) & ~(size_t)255; return r; };
  const size_t WQKV_B = (size_t)3072 * 1024 * 2;        // 6 MB
  const size_t WT_B   = (size_t)1024 * 1024 * 2;        // 2 MB
  const size_t BIG_B  = (size_t)16384 * 1024 * 2;       // 32 MB
  const size_t KVT_B  = (size_t)64 * NCC * 4096 * 2;    // 32 MB bf16
  const size_t KS_B   = (size_t)64 * NCC * 64 * 4;      // 1 MB f32

  u16* WqkvT  = (u16*)(ws + take(WQKV_B));
  u16* WoT    = (u16*)(ws + take(WT_B));
  size_t shared_off = take(BIG_B);                      // xbf -> KVTc -> attn alias chain
  u16* xbf    = (u16*)(ws + shared_off);
  u16* KVTc   = (u16*)(ws + shared_off);
  u16* attn   = (u16*)(ws + shared_off);
  u16* Qb     = (u16*)(ws + take(BIG_B));               // Q|K|V contiguous (3 x 32 MB)
  u16* Kb     = (u16*)(ws + take(BIG_B));
  u16* Vb     = (u16*)(ws + take(BIG_B));
  u16* KVpreT = (u16*)(ws + take(KVT_B));
  float* Ksc  = (float*)(ws + take(KS_B));
  float* Kspre= (float*)(ws + take(KS_B));

  const dim3 blk(256);
  prep_k<<<dim3(12288), blk, 0, stream>>>(x, Wq, Wk, Wv, Wo, xbf, WqkvT, WoT);

  // fused QKV: N=3072 -> Qb/Kb/Vb; grid (N/256, M/128) = (12, 128) = 1536 wg
  gemm128_k<true, false><<<dim3(12, 128), dim3(512), 0, stream>>>(
      xbf, WqkvT, bq, bk, bv, Qb, 16384, 1024);

  const dim3 gC(NCC, Hh, 4);
  chunk_kv_k<<<gC, blk, 0, stream>>>(Kb, Vb, KVTc, Ksc);   // KVTc reuses xbf slot
  prefix_k<<<dim3(64, 4), blk, 0, stream>>>(KVTc, Ksc, KVpreT, Kspre);
  chunk_out_k<<<gC, blk, 0, stream>>>(Qb, Kb, Vb, KVpreT, Kspre, attn);

  // Wo: grid (1024/256, 16384/128) = (4, 128) = 512 wg
  gemm128_k<false, true><<<dim3(4, 128), dim3(512), 0, stream>>>(
      attn, WoT, bo, NULL, NULL, out, 16384, 1024);
}